// Round 1
// baseline (311.861 us; speedup 1.0000x reference)
//
#include <hip/hip_runtime.h>

// BitLinear: LN (no affine) -> global absmax int8 quant -> q @ sign(W-mean(W))^T
//   -> * (maxval/128 * mean|W|) + bias
// x: [4,2048,2048] f32 -> M=8192,K=2048 ; W: [8192,2048] -> N=8192 ; out f32 [8192,8192]

using i32x4 = __attribute__((ext_vector_type(4))) int;

typedef const __attribute__((address_space(1))) void cg_void;
typedef __attribute__((address_space(3))) void lds_void;

__device__ __forceinline__ void gload_lds16(const void* g, void* l) {
    __builtin_amdgcn_global_load_lds((cg_void*)g, (lds_void*)l, 16, 0, 0);
}

#define K_DIM 2048
#define N_DIM 8192
#define M_DIM 8192
#define NELEM_W 16777216   // 8192*2048

// ---- scalars layout in ws (offset 0): [0]=maxbits(u32) [1]=wmean(f32) [2]=beta(f32)
__global__ void init_scalars(unsigned* s) {
    if (threadIdx.x < 16) s[threadIdx.x] = 0u;
}

// ---- weight sum / abs-sum reduction, fp64 accumulation (deterministic tree) ----
__global__ __launch_bounds__(256) void wred1(const float4* __restrict__ w4,
                                             double2* __restrict__ part) {
    double s = 0.0, a = 0.0;
    for (int i = blockIdx.x * 256 + threadIdx.x; i < NELEM_W / 4; i += 1024 * 256) {
        float4 v = w4[i];
        s += (double)v.x + (double)v.y + (double)v.z + (double)v.w;
        a += fabs((double)v.x) + fabs((double)v.y) + fabs((double)v.z) + fabs((double)v.w);
    }
    for (int o = 32; o; o >>= 1) { s += __shfl_xor(s, o); a += __shfl_xor(a, o); }
    __shared__ double sb[8];
    int lane = threadIdx.x & 63, wv = threadIdx.x >> 6;
    if (lane == 0) { sb[wv] = s; sb[4 + wv] = a; }
    __syncthreads();
    if (threadIdx.x == 0) {
        double2 r;
        r.x = sb[0] + sb[1] + sb[2] + sb[3];
        r.y = sb[4] + sb[5] + sb[6] + sb[7];
        part[blockIdx.x] = r;
    }
}

__global__ __launch_bounds__(256) void wred2(const double2* __restrict__ part, unsigned* scal) {
    double s = 0.0, a = 0.0;
    for (int i = threadIdx.x; i < 1024; i += 256) { double2 p = part[i]; s += p.x; a += p.y; }
    for (int o = 32; o; o >>= 1) { s += __shfl_xor(s, o); a += __shfl_xor(a, o); }
    __shared__ double sb[8];
    int lane = threadIdx.x & 63, wv = threadIdx.x >> 6;
    if (lane == 0) { sb[wv] = s; sb[4 + wv] = a; }
    __syncthreads();
    if (threadIdx.x == 0) {
        double st = sb[0] + sb[1] + sb[2] + sb[3];
        double at = sb[4] + sb[5] + sb[6] + sb[7];
        ((float*)scal)[1] = (float)(st / (double)NELEM_W);  // wmean
        ((float*)scal)[2] = (float)(at / (double)NELEM_W);  // beta
    }
}

// ---- per-row LN stats + global absmax of normalized values ----
__global__ __launch_bounds__(256) void ln_stats(const float* __restrict__ x,
                                                float* __restrict__ mu_arr,
                                                float* __restrict__ rstd_arr,
                                                unsigned* __restrict__ scal) {
    __shared__ float sb1[4];
    __shared__ float sb2[8];
    int row = blockIdx.x, t = threadIdx.x;
    const float4* xr = (const float4*)x + (size_t)row * 512;
    float4 v0 = xr[t], v1 = xr[t + 256];
    float s = v0.x + v0.y + v0.z + v0.w + v1.x + v1.y + v1.z + v1.w;
    for (int o = 32; o; o >>= 1) s += __shfl_xor(s, o);
    int lane = t & 63, wv = t >> 6;
    if (lane == 0) sb1[wv] = s;
    __syncthreads();
    float mu = (sb1[0] + sb1[1] + sb1[2] + sb1[3]) * (1.0f / 2048.0f);
    float ssq = 0.f, md = 0.f, d;
    d = v0.x - mu; ssq += d * d; md = fmaxf(md, fabsf(d));
    d = v0.y - mu; ssq += d * d; md = fmaxf(md, fabsf(d));
    d = v0.z - mu; ssq += d * d; md = fmaxf(md, fabsf(d));
    d = v0.w - mu; ssq += d * d; md = fmaxf(md, fabsf(d));
    d = v1.x - mu; ssq += d * d; md = fmaxf(md, fabsf(d));
    d = v1.y - mu; ssq += d * d; md = fmaxf(md, fabsf(d));
    d = v1.z - mu; ssq += d * d; md = fmaxf(md, fabsf(d));
    d = v1.w - mu; ssq += d * d; md = fmaxf(md, fabsf(d));
    for (int o = 32; o; o >>= 1) {
        ssq += __shfl_xor(ssq, o);
        md = fmaxf(md, __shfl_xor(md, o));
    }
    if (lane == 0) { sb2[wv] = ssq; sb2[4 + wv] = md; }
    __syncthreads();
    if (t == 0) {
        float var = (sb2[0] + sb2[1] + sb2[2] + sb2[3]) * (1.0f / 2048.0f);
        float rstd = 1.0f / sqrtf(var + 1e-5f);
        float m = fmaxf(fmaxf(sb2[4], sb2[5]), fmaxf(sb2[6], sb2[7])) * rstd;
        mu_arr[row] = mu;
        rstd_arr[row] = rstd;
        atomicMax(scal, __float_as_uint(m));  // positive floats: bit order == value order
    }
}

// ---- quantize x rows to int8 using global max ----
__global__ __launch_bounds__(256) void quant_x(const float* __restrict__ x,
                                               const float* __restrict__ mu_arr,
                                               const float* __restrict__ rstd_arr,
                                               const unsigned* __restrict__ scal,
                                               signed char* __restrict__ q) {
    int row = blockIdx.x, t = threadIdx.x;
    float mu = mu_arr[row], rstd = rstd_arr[row];
    float maxv = __uint_as_float(scal[0]);
    float s = 128.0f / maxv;
    const float4* xr = (const float4*)x + (size_t)row * 512;
    float4 v0 = xr[2 * t], v1 = xr[2 * t + 1];
    float xs[8] = {v0.x, v0.y, v0.z, v0.w, v1.x, v1.y, v1.z, v1.w};
    int b[8];
    #pragma unroll
    for (int j = 0; j < 8; ++j) {
        float norm = (xs[j] - mu) * rstd;   // matches ref: input_norm rounded first
        float v = norm * s;
        int qi = (int)rintf(v);             // half-even == jnp.round; +128 wraps via &255
        b[j] = qi & 255;
    }
    int w0 = b[0] | (b[1] << 8) | (b[2] << 16) | (b[3] << 24);
    int w1 = b[4] | (b[5] << 8) | (b[6] << 16) | (b[7] << 24);
    ((int2*)(q + (size_t)row * 2048))[t] = make_int2(w0, w1);
}

// ---- binarize weights: sign(w - mean) ----
__device__ __forceinline__ int sgn8(float d) { return (d > 0.f) ? 1 : ((d < 0.f) ? -1 : 0); }

__global__ __launch_bounds__(256) void quant_w(const float4* __restrict__ w4,
                                               const unsigned* __restrict__ scal,
                                               int4* __restrict__ wq4) {
    float wm = ((const float*)scal)[1];
    for (int i = blockIdx.x * 256 + threadIdx.x; i < NELEM_W / 16; i += 1024 * 256) {
        int words[4];
        #pragma unroll
        for (int jj = 0; jj < 4; ++jj) {
            float4 v = w4[i * 4 + jj];
            int b0 = sgn8(v.x - wm) & 255, b1 = sgn8(v.y - wm) & 255;
            int b2 = sgn8(v.z - wm) & 255, b3 = sgn8(v.w - wm) & 255;
            words[jj] = b0 | (b1 << 8) | (b2 << 16) | (b3 << 24);
        }
        wq4[i] = make_int4(words[0], words[1], words[2], words[3]);
    }
}

// ---- int8 GEMM: C[M,N] = q[M,K] . wq[N,K]^T, epilogue scale+bias ----
// m97 structure: 128x128 tile, 4 waves (2x2 of 64x64), BK=64, global_load_lds w=16.
__global__ __launch_bounds__(256) void gemm_i8(const signed char* __restrict__ A,
                                               const signed char* __restrict__ B,
                                               const float* __restrict__ bias,
                                               const unsigned* __restrict__ scal,
                                               float* __restrict__ C) {
    __shared__ alignas(16) signed char at[128 * 64];
    __shared__ alignas(16) signed char bt[128 * 64];
    int t = threadIdx.x;
    int w = t >> 6, lane = t & 63;
    int tm = blockIdx.y * 128, tn = blockIdx.x * 128;
    int wr = (w >> 1) * 64, wc = (w & 1) * 64;
    int r16 = lane & 15, ko = lane >> 4;

    i32x4 acc[4][4] = {};

    int arow = t >> 2;            // 0..63
    int acol = (t & 3) * 16;      // byte offset within BK=64
    const signed char* ga0 = A + (size_t)(tm + arow) * K_DIM + acol;
    const signed char* ga1 = A + (size_t)(tm + arow + 64) * K_DIM + acol;
    const signed char* gb0 = B + (size_t)(tn + arow) * K_DIM + acol;
    const signed char* gb1 = B + (size_t)(tn + arow + 64) * K_DIM + acol;
    signed char* la0 = at + w * 1024;          // wave-uniform LDS base, lane*16 implied
    signed char* la1 = at + 4096 + w * 1024;
    signed char* lb0 = bt + w * 1024;
    signed char* lb1 = bt + 4096 + w * 1024;

    for (int k0 = 0; k0 < K_DIM; k0 += 64) {
        gload_lds16(ga0 + k0, la0);
        gload_lds16(ga1 + k0, la1);
        gload_lds16(gb0 + k0, lb0);
        gload_lds16(gb1 + k0, lb1);
        __syncthreads();   // compiler emits vmcnt(0) drain before barrier

        i32x4 af[4], bf[4];
        #pragma unroll
        for (int m = 0; m < 4; ++m)
            af[m] = *(const i32x4*)(at + (wr + m * 16 + r16) * 64 + ko * 16);
        #pragma unroll
        for (int n = 0; n < 4; ++n)
            bf[n] = *(const i32x4*)(bt + (wc + n * 16 + r16) * 64 + ko * 16);
        #pragma unroll
        for (int m = 0; m < 4; ++m)
            #pragma unroll
            for (int n = 0; n < 4; ++n)
                acc[m][n] = __builtin_amdgcn_mfma_i32_16x16x64_i8(af[m], bf[n], acc[m][n], 0, 0, 0);
        __syncthreads();   // MFMA reads done before next stage overwrites
    }

    float scale = (__uint_as_float(scal[0]) * (1.0f / 128.0f)) * ((const float*)scal)[2];
    float bi[4];
    #pragma unroll
    for (int n = 0; n < 4; ++n) bi[n] = bias[tn + wc + n * 16 + r16];

    #pragma unroll
    for (int m = 0; m < 4; ++m) {
        #pragma unroll
        for (int n = 0; n < 4; ++n) {
            #pragma unroll
            for (int r = 0; r < 4; ++r) {
                int row = tm + wr + m * 16 + ko * 4 + r;   // C/D: row=(lane>>4)*4+reg
                int col = tn + wc + n * 16 + r16;          //      col=lane&15
                C[(size_t)row * N_DIM + col] = (float)acc[m][n][r] * scale + bi[n];
            }
        }
    }
}

extern "C" void kernel_launch(void* const* d_in, const int* in_sizes, int n_in,
                              void* d_out, int out_size, void* d_ws, size_t ws_size,
                              hipStream_t stream) {
    const float* x = (const float*)d_in[0];
    const float* wts = (const float*)d_in[1];
    const float* bias = (const float*)d_in[2];
    float* out = (float*)d_out;

    char* ws = (char*)d_ws;
    unsigned* scal = (unsigned*)ws;                       // 64 B
    double2* part = (double2*)(ws + 1024);                // 16 KB
    float* mu = (float*)(ws + 32768);                     // 32 KB
    float* rstd = (float*)(ws + 65536);                   // 32 KB
    signed char* q = (signed char*)(ws + 98304);          // 16 MB
    signed char* wq = (signed char*)(ws + 98304 + 16777216);  // 16 MB

    hipLaunchKernelGGL(init_scalars, dim3(1), dim3(64), 0, stream, scal);
    hipLaunchKernelGGL(wred1, dim3(1024), dim3(256), 0, stream, (const float4*)wts, part);
    hipLaunchKernelGGL(wred2, dim3(1), dim3(256), 0, stream, part, scal);
    hipLaunchKernelGGL(ln_stats, dim3(8192), dim3(256), 0, stream, x, mu, rstd, scal);
    hipLaunchKernelGGL(quant_x, dim3(8192), dim3(256), 0, stream, x, mu, rstd, scal, q);
    hipLaunchKernelGGL(quant_w, dim3(1024), dim3(256), 0, stream, (const float4*)wts, scal, (int4*)wq);
    hipLaunchKernelGGL(gemm_i8, dim3(64, 64), dim3(256), 0, stream,
                       q, wq, bias, scal, out);
}

// Round 2
// 309.064 us; speedup vs baseline: 1.0090x; 1.0090x over previous
//
#include <hip/hip_runtime.h>

// BitLinear: LN (no affine) -> global absmax int8 quant -> q @ sign(W-mean(W))^T
//   -> * (maxval/128 * mean|W|) + bias
// x: [4,2048,2048] f32 -> M=8192,K=2048 ; W: [8192,2048] -> N=8192 ; out f32 [8192,8192]

using i32x4 = __attribute__((ext_vector_type(4))) int;

typedef const __attribute__((address_space(1))) void cg_void;
typedef __attribute__((address_space(3))) void lds_void;

#define K_DIM 2048
#define N_DIM 8192
#define M_DIM 8192
#define NELEM_W 16777216   // 8192*2048

// ---- scalars layout in ws (offset 0): [0]=maxbits(u32) [1]=wmean(f32) [2]=beta(f32)

// ---- weight sum / abs-sum reduction, fp64 accumulation (deterministic tree) ----
__global__ __launch_bounds__(256) void wred1(const float4* __restrict__ w4,
                                             double2* __restrict__ part) {
    double s = 0.0, a = 0.0;
    for (int i = blockIdx.x * 256 + threadIdx.x; i < NELEM_W / 4; i += 1024 * 256) {
        float4 v = w4[i];
        s += (double)v.x + (double)v.y + (double)v.z + (double)v.w;
        a += fabs((double)v.x) + fabs((double)v.y) + fabs((double)v.z) + fabs((double)v.w);
    }
    for (int o = 32; o; o >>= 1) { s += __shfl_xor(s, o); a += __shfl_xor(a, o); }
    __shared__ double sb[8];
    int lane = threadIdx.x & 63, wv = threadIdx.x >> 6;
    if (lane == 0) { sb[wv] = s; sb[4 + wv] = a; }
    __syncthreads();
    if (threadIdx.x == 0) {
        double2 r;
        r.x = sb[0] + sb[1] + sb[2] + sb[3];
        r.y = sb[4] + sb[5] + sb[6] + sb[7];
        part[blockIdx.x] = r;
    }
}

__global__ __launch_bounds__(256) void wred2(const double2* __restrict__ part, unsigned* scal) {
    double s = 0.0, a = 0.0;
    for (int i = threadIdx.x; i < 1024; i += 256) { double2 p = part[i]; s += p.x; a += p.y; }
    for (int o = 32; o; o >>= 1) { s += __shfl_xor(s, o); a += __shfl_xor(a, o); }
    __shared__ double sb[8];
    int lane = threadIdx.x & 63, wv = threadIdx.x >> 6;
    if (lane == 0) { sb[wv] = s; sb[4 + wv] = a; }
    __syncthreads();
    if (threadIdx.x == 0) {
        double st = sb[0] + sb[1] + sb[2] + sb[3];
        double at = sb[4] + sb[5] + sb[6] + sb[7];
        scal[0] = 0u;                                       // zero absmax slot for ln_stats
        ((float*)scal)[1] = (float)(st / (double)NELEM_W);  // wmean
        ((float*)scal)[2] = (float)(at / (double)NELEM_W);  // beta
    }
}

// ---- per-row LN stats + global absmax of normalized values ----
__global__ __launch_bounds__(256) void ln_stats(const float* __restrict__ x,
                                                float* __restrict__ mu_arr,
                                                float* __restrict__ rstd_arr,
                                                unsigned* __restrict__ scal) {
    __shared__ float sb1[4];
    __shared__ float sb2[8];
    int row = blockIdx.x, t = threadIdx.x;
    const float4* xr = (const float4*)x + (size_t)row * 512;
    float4 v0 = xr[t], v1 = xr[t + 256];
    float s = v0.x + v0.y + v0.z + v0.w + v1.x + v1.y + v1.z + v1.w;
    for (int o = 32; o; o >>= 1) s += __shfl_xor(s, o);
    int lane = t & 63, wv = t >> 6;
    if (lane == 0) sb1[wv] = s;
    __syncthreads();
    float mu = (sb1[0] + sb1[1] + sb1[2] + sb1[3]) * (1.0f / 2048.0f);
    float ssq = 0.f, md = 0.f, d;
    d = v0.x - mu; ssq += d * d; md = fmaxf(md, fabsf(d));
    d = v0.y - mu; ssq += d * d; md = fmaxf(md, fabsf(d));
    d = v0.z - mu; ssq += d * d; md = fmaxf(md, fabsf(d));
    d = v0.w - mu; ssq += d * d; md = fmaxf(md, fabsf(d));
    d = v1.x - mu; ssq += d * d; md = fmaxf(md, fabsf(d));
    d = v1.y - mu; ssq += d * d; md = fmaxf(md, fabsf(d));
    d = v1.z - mu; ssq += d * d; md = fmaxf(md, fabsf(d));
    d = v1.w - mu; ssq += d * d; md = fmaxf(md, fabsf(d));
    for (int o = 32; o; o >>= 1) {
        ssq += __shfl_xor(ssq, o);
        md = fmaxf(md, __shfl_xor(md, o));
    }
    if (lane == 0) { sb2[wv] = ssq; sb2[4 + wv] = md; }
    __syncthreads();
    if (t == 0) {
        float var = (sb2[0] + sb2[1] + sb2[2] + sb2[3]) * (1.0f / 2048.0f);
        float rstd = 1.0f / sqrtf(var + 1e-5f);
        float m = fmaxf(fmaxf(sb2[4], sb2[5]), fmaxf(sb2[6], sb2[7])) * rstd;
        mu_arr[row] = mu;
        rstd_arr[row] = rstd;
        atomicMax(scal, __float_as_uint(m));  // positive floats: bit order == value order
    }
}

// ---- quantize x rows to int8 using global max ----
__global__ __launch_bounds__(256) void quant_x(const float* __restrict__ x,
                                               const float* __restrict__ mu_arr,
                                               const float* __restrict__ rstd_arr,
                                               const unsigned* __restrict__ scal,
                                               signed char* __restrict__ q) {
    int row = blockIdx.x, t = threadIdx.x;
    float mu = mu_arr[row], rstd = rstd_arr[row];
    float maxv = __uint_as_float(scal[0]);
    float s = 128.0f / maxv;
    const float4* xr = (const float4*)x + (size_t)row * 512;
    float4 v0 = xr[2 * t], v1 = xr[2 * t + 1];
    float xs[8] = {v0.x, v0.y, v0.z, v0.w, v1.x, v1.y, v1.z, v1.w};
    int b[8];
    #pragma unroll
    for (int j = 0; j < 8; ++j) {
        float norm = (xs[j] - mu) * rstd;
        float v = norm * s;
        int qi = (int)rintf(v);             // half-even == jnp.round; +128 wraps via &255
        b[j] = qi & 255;
    }
    int w0 = b[0] | (b[1] << 8) | (b[2] << 16) | (b[3] << 24);
    int w1 = b[4] | (b[5] << 8) | (b[6] << 16) | (b[7] << 24);
    ((int2*)(q + (size_t)row * 2048))[t] = make_int2(w0, w1);
}

// ---- binarize weights: sign(w - mean) ----
__device__ __forceinline__ int sgn8(float d) { return (d > 0.f) ? 1 : ((d < 0.f) ? -1 : 0); }

__global__ __launch_bounds__(256) void quant_w(const float4* __restrict__ w4,
                                               const unsigned* __restrict__ scal,
                                               int4* __restrict__ wq4) {
    float wm = ((const float*)scal)[1];
    for (int i = blockIdx.x * 256 + threadIdx.x; i < NELEM_W / 16; i += 1024 * 256) {
        int words[4];
        #pragma unroll
        for (int jj = 0; jj < 4; ++jj) {
            float4 v = w4[i * 4 + jj];
            int b0 = sgn8(v.x - wm) & 255, b1 = sgn8(v.y - wm) & 255;
            int b2 = sgn8(v.z - wm) & 255, b3 = sgn8(v.w - wm) & 255;
            words[jj] = b0 | (b1 << 8) | (b2 << 16) | (b3 << 24);
        }
        wq4[i] = make_int4(words[0], words[1], words[2], words[3]);
    }
}

// ---- int8 GEMM, 256x256 tile, 8-phase schedule (m201 template ported to i8) ----
// 8 waves (2M x 4N), per-wave 128x64 out, BK=128 i8 (=128B rows, same bytes as bf16 BK=64).
// T2 swizzle: LDS byte = row*128 + (col ^ ((row&7)<<4)); global_load_lds dest linear,
// source column pre-swizzled (involution), ds_read address swizzled.
#define LD16(p) (*(const i32x4*)(p))

#define STAGE_TILE(k0, sbase)                                                              \
    do {                                                                                   \
        _Pragma("unroll") for (int i_ = 0; i_ < 4; ++i_)                                   \
            __builtin_amdgcn_global_load_lds((cg_void*)(gA + (size_t)i_ * 131072 + (k0)),  \
                (lds_void*)(lds + (sbase) + i_ * 8192 + w * 1024), 16, 0, 0);              \
        _Pragma("unroll") for (int i_ = 0; i_ < 4; ++i_)                                   \
            __builtin_amdgcn_global_load_lds((cg_void*)(gB + (size_t)i_ * 131072 + (k0)),  \
                (lds_void*)(lds + (sbase) + 32768 + i_ * 8192 + w * 1024), 16, 0, 0);      \
    } while (0)

#define MF16(MB, BF)                                                                       \
    _Pragma("unroll") for (int mm = 0; mm < 4; ++mm)                                       \
        _Pragma("unroll") for (int nn = 0; nn < 4; ++nn)                                   \
            acc[(MB) + mm][nn] = __builtin_amdgcn_mfma_i32_16x16x64_i8(                    \
                af[mm], BF[nn], acc[(MB) + mm][nn], 0, 0, 0);

__global__ __launch_bounds__(512, 2) void gemm_i8(const signed char* __restrict__ A,
                                                  const signed char* __restrict__ B,
                                                  const float* __restrict__ bias,
                                                  const unsigned* __restrict__ scal,
                                                  float* __restrict__ C) {
    __shared__ alignas(16) char lds[131072];   // 2 x (A 32K + B 32K)
    const int t = threadIdx.x, w = t >> 6, lane = t & 63;

    // T1: bijective XCD swizzle (nwg=1024 divisible by 8)
    int wg = blockIdx.x;
    int swz = (wg & 7) * 128 + (wg >> 3);
    int by = swz >> 5, bx = swz & 31;
    int bm = by * 256, bn = bx * 256;

    int wr = w >> 2, wc = w & 3;               // wave grid 2M x 4N
    int r16 = lane & 15, ko = lane >> 4;

    // staging: thread t stages 16B; linear LDS offset t*16 -> (row = i*64 + w*8 + lane>>3,
    // lds col = (lane&7)*16); global source col = lds_col ^ ((row&7)<<4)
    int srow = w * 8 + (lane >> 3);
    int scol = ((lane & 7) ^ (lane >> 3)) << 4;
    const signed char* gA = A + (size_t)(bm + srow) * K_DIM + scol;
    const signed char* gB = B + (size_t)(bn + srow) * K_DIM + scol;

    // fragment reads (swizzled addresses); row&7 == r16&7 for all frag rows
    const char* aBase = lds + (wr * 128 + r16) * 128;
    const char* bBase = lds + 32768 + (wc * 64 + r16) * 128;
    int xr = (r16 & 7) << 4;
    int sw0 = (ko * 16) ^ xr;            // kk=0 slot
    int sw1 = (64 + ko * 16) ^ xr;       // kk=1 slot

    i32x4 acc[8][4] = {};
    i32x4 af[4], bf0[4], bf1[4];

    STAGE_TILE(0, 0);   // prologue: tile 0 -> buf0 (8 loads in flight)

    for (int kt = 0; kt < 15; ++kt) {
        const int c = (kt & 1) << 16;    // compute buffer
        const int s = c ^ 65536;         // stage buffer
        STAGE_TILE((kt + 1) * 128, s);   // issue next tile's 8 loads
        // counted wait: drains previous tile's 8, keeps next tile's 8 in flight
        asm volatile("s_waitcnt vmcnt(8)" ::: "memory");
        __builtin_amdgcn_s_barrier();
        // ---- P0: A m0-3 kk0 + B kk0, MFMA quadrant (m0-3 x n0-3, kk0)
        #pragma unroll
        for (int m = 0; m < 4; ++m) af[m] = LD16(aBase + c + m * 2048 + sw0);
        #pragma unroll
        for (int n = 0; n < 4; ++n) bf0[n] = LD16(bBase + c + n * 2048 + sw0);
        asm volatile("s_waitcnt lgkmcnt(0)" ::: "memory");
        __builtin_amdgcn_s_setprio(1);
        MF16(0, bf0);
        __builtin_amdgcn_s_setprio(0);
        __builtin_amdgcn_s_barrier();
        // ---- P1: A m0-3 kk1 + B kk1
        #pragma unroll
        for (int m = 0; m < 4; ++m) af[m] = LD16(aBase + c + m * 2048 + sw1);
        #pragma unroll
        for (int n = 0; n < 4; ++n) bf1[n] = LD16(bBase + c + n * 2048 + sw1);
        __builtin_amdgcn_s_barrier();
        asm volatile("s_waitcnt lgkmcnt(0)" ::: "memory");
        __builtin_amdgcn_s_setprio(1);
        MF16(0, bf1);
        __builtin_amdgcn_s_setprio(0);
        __builtin_amdgcn_s_barrier();
        // ---- P2: A m4-7 kk0 (B kk0 reused)
        #pragma unroll
        for (int m = 0; m < 4; ++m) af[m] = LD16(aBase + c + (4 + m) * 2048 + sw0);
        __builtin_amdgcn_s_barrier();
        asm volatile("s_waitcnt lgkmcnt(0)" ::: "memory");
        __builtin_amdgcn_s_setprio(1);
        MF16(4, bf0);
        __builtin_amdgcn_s_setprio(0);
        __builtin_amdgcn_s_barrier();
        // ---- P3: A m4-7 kk1 (B kk1 reused)
        #pragma unroll
        for (int m = 0; m < 4; ++m) af[m] = LD16(aBase + c + (4 + m) * 2048 + sw1);
        __builtin_amdgcn_s_barrier();
        asm volatile("s_waitcnt lgkmcnt(0)" ::: "memory");
        __builtin_amdgcn_s_setprio(1);
        MF16(4, bf1);
        __builtin_amdgcn_s_setprio(0);
        __builtin_amdgcn_s_barrier();
    }

    // epilogue tile 15 (buf1): no prefetch, drain everything, compiler-ordered lgkm
    {
        const int c = 65536;
        asm volatile("s_waitcnt vmcnt(0)" ::: "memory");
        __builtin_amdgcn_s_barrier();
        #pragma unroll
        for (int m = 0; m < 4; ++m) af[m] = LD16(aBase + c + m * 2048 + sw0);
        #pragma unroll
        for (int n = 0; n < 4; ++n) bf0[n] = LD16(bBase + c + n * 2048 + sw0);
        MF16(0, bf0);
        #pragma unroll
        for (int m = 0; m < 4; ++m) af[m] = LD16(aBase + c + m * 2048 + sw1);
        #pragma unroll
        for (int n = 0; n < 4; ++n) bf1[n] = LD16(bBase + c + n * 2048 + sw1);
        MF16(0, bf1);
        #pragma unroll
        for (int m = 0; m < 4; ++m) af[m] = LD16(aBase + c + (4 + m) * 2048 + sw0);
        MF16(4, bf0);
        #pragma unroll
        for (int m = 0; m < 4; ++m) af[m] = LD16(aBase + c + (4 + m) * 2048 + sw1);
        MF16(4, bf1);
    }

    float scale = (__uint_as_float(scal[0]) * (1.0f / 128.0f)) * ((const float*)scal)[2];
    int colbase = bn + wc * 64;
    float bi[4];
    #pragma unroll
    for (int n = 0; n < 4; ++n) bi[n] = bias[colbase + n * 16 + r16];

    #pragma unroll
    for (int m = 0; m < 8; ++m) {
        #pragma unroll
        for (int n = 0; n < 4; ++n) {
            #pragma unroll
            for (int r = 0; r < 4; ++r) {
                int row = bm + wr * 128 + m * 16 + ko * 4 + r;  // C/D: row=(lane>>4)*4+reg
                int col = colbase + n * 16 + r16;               //      col=lane&15
                C[(size_t)row * N_DIM + col] = (float)acc[m][n][r] * scale + bi[n];
            }
        }
    }
}

extern "C" void kernel_launch(void* const* d_in, const int* in_sizes, int n_in,
                              void* d_out, int out_size, void* d_ws, size_t ws_size,
                              hipStream_t stream) {
    const float* x = (const float*)d_in[0];
    const float* wts = (const float*)d_in[1];
    const float* bias = (const float*)d_in[2];
    float* out = (float*)d_out;

    char* ws = (char*)d_ws;
    unsigned* scal = (unsigned*)ws;                       // 64 B
    double2* part = (double2*)(ws + 1024);                // 16 KB
    float* mu = (float*)(ws + 32768);                     // 32 KB
    float* rstd = (float*)(ws + 65536);                   // 32 KB
    signed char* q = (signed char*)(ws + 98304);          // 16 MB
    signed char* wq = (signed char*)(ws + 98304 + 16777216);  // 16 MB

    hipLaunchKernelGGL(wred1, dim3(1024), dim3(256), 0, stream, (const float4*)wts, part);
    hipLaunchKernelGGL(wred2, dim3(1), dim3(256), 0, stream, part, scal);
    hipLaunchKernelGGL(ln_stats, dim3(8192), dim3(256), 0, stream, x, mu, rstd, scal);
    hipLaunchKernelGGL(quant_x, dim3(8192), dim3(256), 0, stream, x, mu, rstd, scal, q);
    hipLaunchKernelGGL(quant_w, dim3(1024), dim3(256), 0, stream, (const float4*)wts, scal, (int4*)wq);
    hipLaunchKernelGGL(gemm_i8, dim3(1024), dim3(512), 0, stream,
                       q, wq, bias, scal, out);
}

// Round 3
// 244.316 us; speedup vs baseline: 1.2765x; 1.2650x over previous
//
#include <hip/hip_runtime.h>

// BitLinear: LN (no affine) -> global absmax int8 quant -> q @ sign(W-mean(W))^T
//   -> * (maxval/128 * mean|W|) + bias
// x: [4,2048,2048] f32 -> M=8192,K=2048 ; W: [8192,2048] -> N=8192 ; out f32 [8192,8192]

using i32x4 = __attribute__((ext_vector_type(4))) int;

typedef const __attribute__((address_space(1))) void cg_void;
typedef __attribute__((address_space(3))) void lds_void;

#define K_DIM 2048
#define N_DIM 8192
#define M_DIM 8192
#define NELEM_W 16777216   // 8192*2048

// ws layout: scal@0 ([0]=absmax f32, [1]=wmean, [2]=beta); part@1024; mu@32768;
//            rstd@65536; rowmax@98304; q@131072; wq@131072+16M

// ---- fused pass1: W sum/abs-sum partials (blocks 0..1023) + LN stats (1024..9215) ----
__global__ __launch_bounds__(256) void pass1(const float* __restrict__ x,
                                             const float4* __restrict__ w4,
                                             float* __restrict__ mu_arr,
                                             float* __restrict__ rstd_arr,
                                             float* __restrict__ rowmax,
                                             double2* __restrict__ part) {
    __shared__ double sbd[8];
    __shared__ float sb1[4];
    __shared__ float sb2[8];
    const int bid = blockIdx.x, t = threadIdx.x;
    const int lane = t & 63, wv = t >> 6;
    if (bid < 1024) {
        double s = 0.0, a = 0.0;
        for (int i = bid * 256 + t; i < NELEM_W / 4; i += 1024 * 256) {
            float4 v = w4[i];
            s += (double)v.x + (double)v.y + (double)v.z + (double)v.w;
            a += fabs((double)v.x) + fabs((double)v.y) + fabs((double)v.z) + fabs((double)v.w);
        }
        for (int o = 32; o; o >>= 1) { s += __shfl_xor(s, o); a += __shfl_xor(a, o); }
        if (lane == 0) { sbd[wv] = s; sbd[4 + wv] = a; }
        __syncthreads();
        if (t == 0) {
            double2 r;
            r.x = sbd[0] + sbd[1] + sbd[2] + sbd[3];
            r.y = sbd[4] + sbd[5] + sbd[6] + sbd[7];
            part[bid] = r;
        }
    } else {
        const int row = bid - 1024;
        const float4* xr = (const float4*)x + (size_t)row * 512;
        float4 v0 = xr[t], v1 = xr[t + 256];
        float s = v0.x + v0.y + v0.z + v0.w + v1.x + v1.y + v1.z + v1.w;
        for (int o = 32; o; o >>= 1) s += __shfl_xor(s, o);
        if (lane == 0) sb1[wv] = s;
        __syncthreads();
        float mu = (sb1[0] + sb1[1] + sb1[2] + sb1[3]) * (1.0f / 2048.0f);
        float ssq = 0.f, md = 0.f, d;
        d = v0.x - mu; ssq += d * d; md = fmaxf(md, fabsf(d));
        d = v0.y - mu; ssq += d * d; md = fmaxf(md, fabsf(d));
        d = v0.z - mu; ssq += d * d; md = fmaxf(md, fabsf(d));
        d = v0.w - mu; ssq += d * d; md = fmaxf(md, fabsf(d));
        d = v1.x - mu; ssq += d * d; md = fmaxf(md, fabsf(d));
        d = v1.y - mu; ssq += d * d; md = fmaxf(md, fabsf(d));
        d = v1.z - mu; ssq += d * d; md = fmaxf(md, fabsf(d));
        d = v1.w - mu; ssq += d * d; md = fmaxf(md, fabsf(d));
        for (int o = 32; o; o >>= 1) {
            ssq += __shfl_xor(ssq, o);
            md = fmaxf(md, __shfl_xor(md, o));
        }
        if (lane == 0) { sb2[wv] = ssq; sb2[4 + wv] = md; }
        __syncthreads();
        if (t == 0) {
            float var = (sb2[0] + sb2[1] + sb2[2] + sb2[3]) * (1.0f / 2048.0f);
            float rstd = 1.0f / sqrtf(var + 1e-5f);
            mu_arr[row] = mu;
            rstd_arr[row] = rstd;
            rowmax[row] = fmaxf(fmaxf(sb2[4], sb2[5]), fmaxf(sb2[6], sb2[7])) * rstd;
        }
    }
}

// ---- wred2: finalize wmean/beta + global absmax (no atomics, no init kernel) ----
__global__ __launch_bounds__(256) void wred2(const double2* __restrict__ part,
                                             const float* __restrict__ rowmax,
                                             unsigned* __restrict__ scal) {
    double s = 0.0, a = 0.0;
    float m = 0.f;
    const int t = threadIdx.x, lane = t & 63, wv = t >> 6;
    for (int i = t; i < 1024; i += 256) { double2 p = part[i]; s += p.x; a += p.y; }
    for (int i = t; i < 8192; i += 256) m = fmaxf(m, rowmax[i]);
    for (int o = 32; o; o >>= 1) {
        s += __shfl_xor(s, o); a += __shfl_xor(a, o);
        m = fmaxf(m, __shfl_xor(m, o));
    }
    __shared__ double sbd[8];
    __shared__ float sbm[4];
    if (lane == 0) { sbd[wv] = s; sbd[4 + wv] = a; sbm[wv] = m; }
    __syncthreads();
    if (t == 0) {
        double st = sbd[0] + sbd[1] + sbd[2] + sbd[3];
        double at = sbd[4] + sbd[5] + sbd[6] + sbd[7];
        ((float*)scal)[0] = fmaxf(fmaxf(sbm[0], sbm[1]), fmaxf(sbm[2], sbm[3]));
        ((float*)scal)[1] = (float)(st / (double)NELEM_W);  // wmean
        ((float*)scal)[2] = (float)(at / (double)NELEM_W);  // beta
    }
}

// ---- fused pass2: quant_w (blocks 0..1023) + quant_x (1024..9215) ----
__device__ __forceinline__ int sgn8(float d) { return (d > 0.f) ? 1 : ((d < 0.f) ? -1 : 0); }

__global__ __launch_bounds__(256) void pass2(const float* __restrict__ x,
                                             const float4* __restrict__ w4,
                                             const float* __restrict__ mu_arr,
                                             const float* __restrict__ rstd_arr,
                                             const unsigned* __restrict__ scal,
                                             signed char* __restrict__ q,
                                             int4* __restrict__ wq4) {
    const int bid = blockIdx.x, t = threadIdx.x;
    if (bid < 1024) {
        float wm = ((const float*)scal)[1];
        for (int i = bid * 256 + t; i < NELEM_W / 16; i += 1024 * 256) {
            int words[4];
            #pragma unroll
            for (int jj = 0; jj < 4; ++jj) {
                float4 v = w4[i * 4 + jj];
                int b0 = sgn8(v.x - wm) & 255, b1 = sgn8(v.y - wm) & 255;
                int b2 = sgn8(v.z - wm) & 255, b3 = sgn8(v.w - wm) & 255;
                words[jj] = b0 | (b1 << 8) | (b2 << 16) | (b3 << 24);
            }
            wq4[i] = make_int4(words[0], words[1], words[2], words[3]);
        }
    } else {
        const int row = bid - 1024;
        float mu = mu_arr[row], rstd = rstd_arr[row];
        float s = 128.0f / ((const float*)scal)[0];
        const float4* xr = (const float4*)x + (size_t)row * 512;
        float4 v0 = xr[2 * t], v1 = xr[2 * t + 1];
        float xs[8] = {v0.x, v0.y, v0.z, v0.w, v1.x, v1.y, v1.z, v1.w};
        int b[8];
        #pragma unroll
        for (int j = 0; j < 8; ++j) {
            float norm = (xs[j] - mu) * rstd;
            int qi = (int)rintf(norm * s);   // half-even == jnp.round; +128 wraps via &255
            b[j] = qi & 255;
        }
        int w0 = b[0] | (b[1] << 8) | (b[2] << 16) | (b[3] << 24);
        int w1 = b[4] | (b[5] << 8) | (b[6] << 16) | (b[7] << 24);
        ((int2*)(q + (size_t)row * 2048))[t] = make_int2(w0, w1);
    }
}

// ---- persistent int8 GEMM: grid=256 (1 block/CU), 4 output tiles per block ----
// 256x256 tile, 8 waves (2Mx4N), BK=128, 8-phase schedule, T2 swizzle, counted vmcnt.
// Tile map: xcd=wg&7, j=wg>>3, row=xcd*4+(j>>3), col(rep)=(j&7)*4+rep -> A panel fixed
// per block (L2-resident across reps); pipeline never drains across rep boundaries.
#define LD16(p) (*(const i32x4*)(p))

#define STAGE(aoff, boff, sbase)                                                            \
    do {                                                                                    \
        _Pragma("unroll") for (int i_ = 0; i_ < 4; ++i_)                                    \
            __builtin_amdgcn_global_load_lds((cg_void*)(gA + (size_t)i_ * 131072 + (aoff)), \
                (lds_void*)(lds + (sbase) + i_ * 8192 + w * 1024), 16, 0, 0);               \
        _Pragma("unroll") for (int i_ = 0; i_ < 4; ++i_)                                    \
            __builtin_amdgcn_global_load_lds((cg_void*)(gB + (size_t)i_ * 131072 + (boff)), \
                (lds_void*)(lds + (sbase) + 32768 + i_ * 8192 + w * 1024), 16, 0, 0);       \
    } while (0)

#define MF16(MB, BF)                                                                        \
    _Pragma("unroll") for (int mm = 0; mm < 4; ++mm)                                        \
        _Pragma("unroll") for (int nn = 0; nn < 4; ++nn)                                    \
            acc[(MB) + mm][nn] = __builtin_amdgcn_mfma_i32_16x16x64_i8(                     \
                af[mm], BF[nn], acc[(MB) + mm][nn], 0, 0, 0);

__global__ __launch_bounds__(512, 2) void gemm_i8(const signed char* __restrict__ A,
                                                  const signed char* __restrict__ B,
                                                  const float* __restrict__ bias,
                                                  const unsigned* __restrict__ scal,
                                                  float* __restrict__ C) {
    __shared__ alignas(16) char lds[131072];   // 2 x (A 32K + B 32K)
    const int t = threadIdx.x, w = t >> 6, lane = t & 63;

    const int wg = blockIdx.x;
    const int xcd = wg & 7, j = wg >> 3;
    const int bm = (xcd * 4 + (j >> 3)) * 256;
    const int col0 = (j & 7) * 4;              // tile-col for rep r is col0 + r

    const int wr = w >> 2, wc = w & 3;         // wave grid 2M x 4N
    const int r16 = lane & 15, ko = lane >> 4;

    // staging: thread stages 16B; LDS dest linear (base+lane*16); global source col
    // pre-swizzled with the involution col ^ ((row&7)<<4)
    const int srow = w * 8 + (lane >> 3);
    const int scol = ((lane & 7) ^ (lane >> 3)) << 4;
    const signed char* gA = A + (size_t)(bm + srow) * K_DIM + scol;
    const signed char* gB = B + (size_t)(col0 * 256 + srow) * K_DIM + scol;

    // fragment reads (swizzled)
    const char* aBase = lds + (wr * 128 + r16) * 128;
    const char* bBase = lds + 32768 + (wc * 64 + r16) * 128;
    const int xr = (r16 & 7) << 4;
    const int sw0 = (ko * 16) ^ xr;            // kk=0 slot
    const int sw1 = (64 + ko * 16) ^ xr;       // kk=1 slot

    const float scale = (((const float*)scal)[0] * (1.0f / 128.0f)) * ((const float*)scal)[2];

    i32x4 acc[8][4] = {};
    i32x4 af[4], bf0[4], bf1[4];

    STAGE(0, 0, 0);   // prologue: rep0 tile0 -> buf0

    #pragma unroll 2
    for (int gt = 0; gt < 64; ++gt) {
        const int c = (gt & 1) << 16;          // compute buffer
        if (gt < 63) {
            const int nt = gt + 1;
            const int kt1 = nt & 15, rep1 = nt >> 4;
            const size_t aoff = (size_t)(kt1 * 128);
            const size_t boff = (size_t)rep1 * 524288 + (size_t)(kt1 * 128);
            STAGE(aoff, boff, (nt & 1) << 16); // issue next tile's 8 loads
            asm volatile("s_waitcnt vmcnt(8)" ::: "memory");  // prev tile's loads done
        } else {
            asm volatile("s_waitcnt vmcnt(0)" ::: "memory");
        }
        __builtin_amdgcn_s_barrier();
        // ---- P0: A m0-3 kk0 + B kk0
        #pragma unroll
        for (int m = 0; m < 4; ++m) af[m] = LD16(aBase + c + m * 2048 + sw0);
        #pragma unroll
        for (int n = 0; n < 4; ++n) bf0[n] = LD16(bBase + c + n * 2048 + sw0);
        asm volatile("s_waitcnt lgkmcnt(0)" ::: "memory");
        __builtin_amdgcn_s_setprio(1);
        MF16(0, bf0);
        __builtin_amdgcn_s_setprio(0);
        __builtin_amdgcn_s_barrier();
        // ---- P1: A m0-3 kk1 + B kk1
        #pragma unroll
        for (int m = 0; m < 4; ++m) af[m] = LD16(aBase + c + m * 2048 + sw1);
        #pragma unroll
        for (int n = 0; n < 4; ++n) bf1[n] = LD16(bBase + c + n * 2048 + sw1);
        __builtin_amdgcn_s_barrier();
        asm volatile("s_waitcnt lgkmcnt(0)" ::: "memory");
        __builtin_amdgcn_s_setprio(1);
        MF16(0, bf1);
        __builtin_amdgcn_s_setprio(0);
        __builtin_amdgcn_s_barrier();
        // ---- P2: A m4-7 kk0 (B kk0 reused)
        #pragma unroll
        for (int m = 0; m < 4; ++m) af[m] = LD16(aBase + c + (4 + m) * 2048 + sw0);
        __builtin_amdgcn_s_barrier();
        asm volatile("s_waitcnt lgkmcnt(0)" ::: "memory");
        __builtin_amdgcn_s_setprio(1);
        MF16(4, bf0);
        __builtin_amdgcn_s_setprio(0);
        __builtin_amdgcn_s_barrier();
        // ---- P3: A m4-7 kk1 (B kk1 reused)
        #pragma unroll
        for (int m = 0; m < 4; ++m) af[m] = LD16(aBase + c + (4 + m) * 2048 + sw1);
        __builtin_amdgcn_s_barrier();
        asm volatile("s_waitcnt lgkmcnt(0)" ::: "memory");
        __builtin_amdgcn_s_setprio(1);
        MF16(4, bf1);
        __builtin_amdgcn_s_setprio(0);
        __builtin_amdgcn_s_barrier();

        // ---- rep boundary: write C, reset acc. Next rep's tile0 loads are already
        // in flight; stores retire at L2-ack (write-back TCC) so the next vmcnt(8)
        // costs only the ack latency.
        if ((gt & 15) == 15) {
            const int rep = gt >> 4;
            const int colbase = (col0 + rep) * 256 + wc * 64;
            float bi[4];
            #pragma unroll
            for (int n = 0; n < 4; ++n) bi[n] = bias[colbase + n * 16 + r16];
            #pragma unroll
            for (int m = 0; m < 8; ++m) {
                #pragma unroll
                for (int n = 0; n < 4; ++n) {
                    #pragma unroll
                    for (int r = 0; r < 4; ++r) {
                        int row = bm + wr * 128 + m * 16 + ko * 4 + r;
                        int col = colbase + n * 16 + r16;
                        C[(size_t)row * N_DIM + col] = (float)acc[m][n][r] * scale + bi[n];
                    }
                }
            }
            #pragma unroll
            for (int m = 0; m < 8; ++m)
                #pragma unroll
                for (int n = 0; n < 4; ++n) acc[m][n] = (i32x4){0, 0, 0, 0};
        }
    }
}

extern "C" void kernel_launch(void* const* d_in, const int* in_sizes, int n_in,
                              void* d_out, int out_size, void* d_ws, size_t ws_size,
                              hipStream_t stream) {
    const float* x = (const float*)d_in[0];
    const float* wts = (const float*)d_in[1];
    const float* bias = (const float*)d_in[2];
    float* out = (float*)d_out;

    char* ws = (char*)d_ws;
    unsigned* scal = (unsigned*)ws;                       // 64 B
    double2* part = (double2*)(ws + 1024);                // 16 KB
    float* mu = (float*)(ws + 32768);                     // 32 KB
    float* rstd = (float*)(ws + 65536);                   // 32 KB
    float* rowmax = (float*)(ws + 98304);                 // 32 KB
    signed char* q = (signed char*)(ws + 131072);         // 16 MB
    signed char* wq = (signed char*)(ws + 131072 + 16777216);  // 16 MB

    hipLaunchKernelGGL(pass1, dim3(9216), dim3(256), 0, stream,
                       x, (const float4*)wts, mu, rstd, rowmax, part);
    hipLaunchKernelGGL(wred2, dim3(1), dim3(256), 0, stream, part, rowmax, scal);
    hipLaunchKernelGGL(pass2, dim3(9216), dim3(256), 0, stream,
                       x, (const float4*)wts, mu, rstd, scal, q, (int4*)wq);
    hipLaunchKernelGGL(gemm_i8, dim3(256), dim3(512), 0, stream,
                       q, wq, bias, scal, out);
}